// Round 1
// 389.932 us; speedup vs baseline: 1.0458x; 1.0458x over previous
//
#include <hip/hip_runtime.h>
#include <math.h>

#define B 8
#define T 128
#define S_ENC 400
#define H 256
#define V 50257
#define HASH_SZ 1024   // power of 2, load factor 400/1024

typedef float vfloat4 __attribute__((ext_vector_type(4)));  // nontemporal-compatible

// ---------------------------------------------------------------------------
// Workspace layout (total ~1.68 MB):
//   params : float4[B*T]              @ 0                (16384 B)
//   u      : int[B][S_ENC]            @ 16384            (12800 B)  unique tokens (unsorted)
//   rnk    : int[B][S_ENC]            @ 29184            (12800 B)  s -> rank in u
//   cnt    : int[B]                   @ 41984            (32 B)
//   vs     : float[B*T][S_ENC]        @ 42048            (1638400 B) (1-p)*merged_attn
// ---------------------------------------------------------------------------

// Kernel A: one block per batch b (8 blocks). Dedup tokens via LDS hash,
// emit unique token list u[b], rank map rnk[b][s], count cnt[b].
// Token lists depend only on b, not t — do this once per b, not per (b,t).
__global__ __launch_bounds__(256) void build_kernel(
    const int* __restrict__ tokens,
    int* __restrict__ u, int* __restrict__ rnk, int* __restrict__ cnt)
{
    __shared__ int hk[HASH_SZ];
    __shared__ int hr[HASH_SZ];
    __shared__ int c;
    const int b = blockIdx.x, tid = threadIdx.x;

    for (int i = tid; i < HASH_SZ; i += 256) hk[i] = -1;
    if (tid == 0) c = 0;
    __syncthreads();

    for (int s = tid; s < S_ENC; s += 256) {
        const int tk = tokens[b * S_ENC + s];
        unsigned h = ((unsigned)tk * 2654435761u >> 16) & (HASH_SZ - 1);
        for (;;) {
            int prev = atomicCAS(&hk[h], -1, tk);
            if (prev == -1 || prev == tk) break;
            h = (h + 1) & (HASH_SZ - 1);
        }
    }
    __syncthreads();

    for (int i = tid; i < HASH_SZ; i += 256) {
        if (hk[i] != -1) {
            const int r = atomicAdd(&c, 1);
            hr[i] = r;
            u[b * S_ENC + r] = hk[i];
        }
    }
    __syncthreads();

    for (int s = tid; s < S_ENC; s += 256) {
        const int tk = tokens[b * S_ENC + s];
        unsigned h = ((unsigned)tk * 2654435761u >> 16) & (HASH_SZ - 1);
        while (hk[h] != tk) h = (h + 1) & (HASH_SZ - 1);
        rnk[b * S_ENC + s] = hr[h];
    }
    if (tid == 0) cnt[b] = c;
}

// ---------------------------------------------------------------------------
// Kernel B: one block per (b,t). p_gen + merged sparse values (dense 400-slot
// array via precomputed rank map — no hash probing, no 1024-slot rescans),
// logsumexp, writes params[bt] = (p, (1-p)*lse, (1-p), 0) and
// vs[bt][r] = (1-p)*val[r].
// ---------------------------------------------------------------------------
__global__ __launch_bounds__(256) void prep_kernel(
    const float* __restrict__ context,
    const float* __restrict__ dec_in,
    const float* __restrict__ dec_out,
    const float* __restrict__ attn,
    const float* __restrict__ Wc, const float* __restrict__ bc,
    const float* __restrict__ Wo, const float* __restrict__ bo,
    const float* __restrict__ Wi, const float* __restrict__ bi,
    const int* __restrict__ rnk, const int* __restrict__ cnt,
    float4* __restrict__ params, float* __restrict__ vs)
{
    __shared__ float val[S_ENC];
    __shared__ float s_pg[4], s_m[4], s_se[4];
    __shared__ float s_mb, s_q;
    const int bt   = blockIdx.x;
    const int b    = bt >> 7;            // T = 128
    const int tid  = threadIdx.x;
    const int lane = tid & 63;
    const int wave = tid >> 6;

    for (int i = tid; i < S_ENC; i += 256) val[i] = 0.0f;

    // p_gen partial: H == 256 == blockDim, one element per thread
    {
        float v = context[bt * H + tid] * Wc[tid]
                + dec_out[bt * H + tid] * Wo[tid]
                + dec_in [bt * H + tid] * Wi[tid];
        #pragma unroll
        for (int off = 32; off; off >>= 1) v += __shfl_down(v, off, 64);
        if (lane == 0) s_pg[wave] = v;
    }
    __syncthreads();

    for (int s = tid; s < S_ENC; s += 256)
        atomicAdd(&val[rnk[b * S_ENC + s]], attn[bt * S_ENC + s]);
    __syncthreads();

    const int n = cnt[b];
    {
        float m = 0.0f;   // zero entries exist (V >> n) so max >= 0
        for (int i = tid; i < n; i += 256) m = fmaxf(m, val[i]);
        #pragma unroll
        for (int off = 32; off; off >>= 1) m = fmaxf(m, __shfl_down(m, off, 64));
        if (lane == 0) s_m[wave] = m;
    }
    __syncthreads();
    if (tid == 0) s_mb = fmaxf(fmaxf(s_m[0], s_m[1]), fmaxf(s_m[2], s_m[3]));
    __syncthreads();
    {
        const float m = s_mb;
        float se = 0.0f;
        for (int i = tid; i < n; i += 256) se += expf(val[i] - m);
        #pragma unroll
        for (int off = 32; off; off >>= 1) se += __shfl_down(se, off, 64);
        if (lane == 0) s_se[wave] = se;
    }
    __syncthreads();
    if (tid == 0) {
        const float m   = s_mb;
        float se  = s_se[0] + s_se[1] + s_se[2] + s_se[3]
                  + (float)(V - n) * expf(-m);
        float lse = m + logf(se);
        float x   = s_pg[0] + s_pg[1] + s_pg[2] + s_pg[3]
                  + bc[0] + bo[0] + bi[0];
        float p   = 1.0f / (1.0f + expf(-x));
        float q   = 1.0f - p;
        params[bt] = make_float4(p, q * lse, q, 0.0f);
        s_q = q;
    }
    __syncthreads();
    const float q = s_q;
    for (int i = tid; i < n; i += 256) vs[bt * S_ENC + i] = q * val[i];
}

// ---------------------------------------------------------------------------
// Kernel C: fused streaming mix + sparse copy scatter. Each block owns 1024
// contiguous output elements (<= 2 rows). Coalesced scan of the per-b unique
// token list stashes in-range hits (expected ~8) into LDS; each thread applies
// the stash to its 4 register outputs via LDS broadcasts. No global atomics,
// no second pass over out — single nontemporal store.
// ---------------------------------------------------------------------------
#define STASH_MAX 800   // hard bound: <= 2 rows x <= 400 entries each

__global__ __launch_bounds__(256) void mix_kernel(
    const vfloat4* __restrict__ vocab,
    const float4*  __restrict__ params,
    const int*     __restrict__ u,
    const int*     __restrict__ cnt,
    const float*   __restrict__ vs,
    vfloat4* __restrict__ out)
{
    __shared__ int   s_d[STASH_MAX];
    __shared__ float s_v[STASH_MAX];
    __shared__ int   s_k;
    const int tid = threadIdx.x;
    const int idx = blockIdx.x * 256 + tid;        // < B*T*V/4
    const int e0  = blockIdx.x << 10;              // block's global element base
    const int bt0 = e0 / V;                        // magic-mul (V constexpr)
    const int btL = (e0 + 1023) / V;

    if (tid == 0) s_k = 0;
    vfloat4 v = __builtin_nontemporal_load(&vocab[idx]);
    __syncthreads();

    // stash sparse entries landing in [e0, e0+1024)
    for (int r = bt0; r <= btL; ++r) {
        const int base = r * V;
        const int bb   = r >> 7;
        const int n    = cnt[bb];
        const int*   ub = u  + bb * S_ENC;
        const float* vb = vs + r  * S_ENC;
        for (int i = tid; i < n; i += 256) {
            const int d = base + ub[i] - e0;
            if ((unsigned)d < 1024u) {
                const int slot = atomicAdd(&s_k, 1);
                s_d[slot] = d;
                s_v[slot] = vb[i];
            }
        }
    }
    __syncthreads();

    // baseline mix: out = vocab*p - (1-p)*lse
    vfloat4 o;
    const int eb = idx << 2;
    if (bt0 == btL) {
        const float4 P = params[bt0];
        o = v * P.x - P.y;
    } else {
        #pragma unroll
        for (int j = 0; j < 4; ++j) {
            const int bt = (eb + j) / V;
            const float4 P = params[bt];
            o[j] = v[j] * P.x - P.y;
        }
    }

    // apply sparse copy contributions (LDS broadcast reads, static reg index)
    const int k  = s_k;
    const int my = eb - e0;                        // == tid*4
    for (int j = 0; j < k; ++j) {
        const int   d = s_d[j] - my;
        const float a = s_v[j];
        o[0] += (d == 0) ? a : 0.0f;
        o[1] += (d == 1) ? a : 0.0f;
        o[2] += (d == 2) ? a : 0.0f;
        o[3] += (d == 3) ? a : 0.0f;
    }
    __builtin_nontemporal_store(o, &out[idx]);
}

extern "C" void kernel_launch(void* const* d_in, const int* in_sizes, int n_in,
                              void* d_out, int out_size, void* d_ws, size_t ws_size,
                              hipStream_t stream) {
    const int*   tokens  = (const int*)  d_in[0];
    const float* context = (const float*)d_in[1];
    const float* dec_in  = (const float*)d_in[2];
    const float* dec_out = (const float*)d_in[3];
    const float* vocab   = (const float*)d_in[4];
    const float* attn    = (const float*)d_in[5];
    // d_in[6] = encoder_outputs (unused by reference)
    const float* Wc = (const float*)d_in[7];
    const float* bc = (const float*)d_in[8];
    const float* Wo = (const float*)d_in[9];
    const float* bo = (const float*)d_in[10];
    const float* Wi = (const float*)d_in[11];
    const float* bi = (const float*)d_in[12];

    float* out = (float*)d_out;
    char*  ws  = (char*)d_ws;
    float4* params = (float4*)ws;                        // 16384 B
    int*    u      = (int*)  (ws + 16384);               // 12800 B
    int*    rnk    = (int*)  (ws + 29184);               // 12800 B
    int*    cnt    = (int*)  (ws + 41984);               // 32 B
    float*  vs     = (float*)(ws + 42048);               // 1638400 B

    build_kernel<<<B, 256, 0, stream>>>(tokens, u, rnk, cnt);

    prep_kernel<<<B * T, 256, 0, stream>>>(context, dec_in, dec_out, attn,
                                           Wc, bc, Wo, bo, Wi, bi,
                                           rnk, cnt, params, vs);

    const int total4 = (B * T * V) / 4;                  // 12,865,792
    mix_kernel<<<total4 / 256, 256, 0, stream>>>(        // 50,257 blocks
        (const vfloat4*)vocab, (const float4*)params, u, cnt, vs, (vfloat4*)out);
}

// Round 2
// 369.626 us; speedup vs baseline: 1.1032x; 1.0549x over previous
//
#include <hip/hip_runtime.h>
#include <math.h>

#define B 8
#define T 128
#define S_ENC 400
#define H 256
#define V 50257
#define HASH_SZ 1024        // power of 2, load factor 400/1024
#define NTOT (B * T * V)    // 51,463,168 elements (divisible by 4)
#define TOTAL4 (NTOT / 4)   // 12,865,792 float4
#define EPB 2048            // elements per mix block
#define QPB (EPB / 4)       // float4 per mix block

typedef float vfloat4 __attribute__((ext_vector_type(4)));  // nontemporal-compatible

// ---------------------------------------------------------------------------
// Workspace layout (total ~1.68 MB):
//   params : float4[B*T]              @ 0                (16384 B)
//   u      : int[B][S_ENC]            @ 16384            (12800 B)  unique tokens
//   rnk    : int[B][S_ENC]            @ 29184            (12800 B)  s -> rank in u
//   cnt    : int[B]                   @ 41984            (32 B)
//   vs     : float[B*T][S_ENC]        @ 42048            (1638400 B) (1-p)*merged_attn
// ---------------------------------------------------------------------------

// Kernel A: one block per batch b (8 blocks). Dedup tokens via LDS hash,
// emit unique token list u[b], rank map rnk[b][s], count cnt[b].
__global__ __launch_bounds__(256) void build_kernel(
    const int* __restrict__ tokens,
    int* __restrict__ u, int* __restrict__ rnk, int* __restrict__ cnt)
{
    __shared__ int hk[HASH_SZ];
    __shared__ int hr[HASH_SZ];
    __shared__ int c;
    const int b = blockIdx.x, tid = threadIdx.x;

    for (int i = tid; i < HASH_SZ; i += 256) hk[i] = -1;
    if (tid == 0) c = 0;
    __syncthreads();

    for (int s = tid; s < S_ENC; s += 256) {
        const int tk = tokens[b * S_ENC + s];
        unsigned h = ((unsigned)tk * 2654435761u >> 16) & (HASH_SZ - 1);
        for (;;) {
            int prev = atomicCAS(&hk[h], -1, tk);
            if (prev == -1 || prev == tk) break;
            h = (h + 1) & (HASH_SZ - 1);
        }
    }
    __syncthreads();

    for (int i = tid; i < HASH_SZ; i += 256) {
        if (hk[i] != -1) {
            const int r = atomicAdd(&c, 1);
            hr[i] = r;
            u[b * S_ENC + r] = hk[i];
        }
    }
    __syncthreads();

    for (int s = tid; s < S_ENC; s += 256) {
        const int tk = tokens[b * S_ENC + s];
        unsigned h = ((unsigned)tk * 2654435761u >> 16) & (HASH_SZ - 1);
        while (hk[h] != tk) h = (h + 1) & (HASH_SZ - 1);
        rnk[b * S_ENC + s] = hr[h];
    }
    if (tid == 0) cnt[b] = c;
}

// ---------------------------------------------------------------------------
// Kernel B: one block per (b,t). p_gen + merged sparse values (dense 400-slot
// array via precomputed rank map), logsumexp, writes
// params[bt] = (p, (1-p)*lse, (1-p), 0) and vs[bt][r] = (1-p)*val[r].
// ---------------------------------------------------------------------------
__global__ __launch_bounds__(256) void prep_kernel(
    const float* __restrict__ context,
    const float* __restrict__ dec_in,
    const float* __restrict__ dec_out,
    const float* __restrict__ attn,
    const float* __restrict__ Wc, const float* __restrict__ bc,
    const float* __restrict__ Wo, const float* __restrict__ bo,
    const float* __restrict__ Wi, const float* __restrict__ bi,
    const int* __restrict__ rnk, const int* __restrict__ cnt,
    float4* __restrict__ params, float* __restrict__ vs)
{
    __shared__ float val[S_ENC];
    __shared__ float s_pg[4], s_m[4], s_se[4];
    __shared__ float s_mb, s_q;
    const int bt   = blockIdx.x;
    const int b    = bt >> 7;            // T = 128
    const int tid  = threadIdx.x;
    const int lane = tid & 63;
    const int wave = tid >> 6;

    for (int i = tid; i < S_ENC; i += 256) val[i] = 0.0f;

    // p_gen partial: H == 256 == blockDim, one element per thread
    {
        float v = context[bt * H + tid] * Wc[tid]
                + dec_out[bt * H + tid] * Wo[tid]
                + dec_in [bt * H + tid] * Wi[tid];
        #pragma unroll
        for (int off = 32; off; off >>= 1) v += __shfl_down(v, off, 64);
        if (lane == 0) s_pg[wave] = v;
    }
    __syncthreads();

    for (int s = tid; s < S_ENC; s += 256)
        atomicAdd(&val[rnk[b * S_ENC + s]], attn[bt * S_ENC + s]);
    __syncthreads();

    const int n = cnt[b];
    {
        float m = 0.0f;   // zero entries exist (V >> n) so max >= 0
        for (int i = tid; i < n; i += 256) m = fmaxf(m, val[i]);
        #pragma unroll
        for (int off = 32; off; off >>= 1) m = fmaxf(m, __shfl_down(m, off, 64));
        if (lane == 0) s_m[wave] = m;
    }
    __syncthreads();
    if (tid == 0) s_mb = fmaxf(fmaxf(s_m[0], s_m[1]), fmaxf(s_m[2], s_m[3]));
    __syncthreads();
    {
        const float m = s_mb;
        float se = 0.0f;
        for (int i = tid; i < n; i += 256) se += expf(val[i] - m);
        #pragma unroll
        for (int off = 32; off; off >>= 1) se += __shfl_down(se, off, 64);
        if (lane == 0) s_se[wave] = se;
    }
    __syncthreads();
    if (tid == 0) {
        const float m   = s_mb;
        float se  = s_se[0] + s_se[1] + s_se[2] + s_se[3]
                  + (float)(V - n) * expf(-m);
        float lse = m + logf(se);
        float x   = s_pg[0] + s_pg[1] + s_pg[2] + s_pg[3]
                  + bc[0] + bo[0] + bi[0];
        float p   = 1.0f / (1.0f + expf(-x));
        float q   = 1.0f - p;
        params[bt] = make_float4(p, q * lse, q, 0.0f);
        s_q = q;
    }
    __syncthreads();
    const float q = s_q;
    for (int i = tid; i < n; i += 256) vs[bt * S_ENC + i] = q * val[i];
}

// ---------------------------------------------------------------------------
// Kernel C: fused streaming mix + sparse copy via direct-scatter LDS tile.
// Each block owns 2048 contiguous elements (2 float4/thread). Sparse entries
// landing in-range are scattered straight into an 8KB LDS tile — provably
// collision-free (tokens unique per row; rows offset by V > EPB), so plain
// stores, no atomics, no stash. Apply = one ds_read_b128 per output vector.
// NT vocab loads issued before zero/scan so HBM latency hides under them.
// ---------------------------------------------------------------------------
__global__ __launch_bounds__(256) void mix_kernel(
    const vfloat4* __restrict__ vocab,
    const float4*  __restrict__ params,
    const int*     __restrict__ u,
    const int*     __restrict__ cnt,
    const float*   __restrict__ vs,
    vfloat4* __restrict__ out)
{
    __shared__ float tile[EPB];
    const int tid = threadIdx.x;
    const int q0  = blockIdx.x * QPB + tid;
    const int q1  = q0 + 256;
    const int e0  = blockIdx.x * EPB;
    const int eL  = min(e0 + EPB - 1, NTOT - 1);
    const int bt0 = e0 / V;                        // magic-mul (V constexpr)
    const int btL = eL / V;

    const bool p0 = q0 < TOTAL4;
    const bool p1 = q1 < TOTAL4;
    vfloat4 v0 = {0.f, 0.f, 0.f, 0.f}, v1 = {0.f, 0.f, 0.f, 0.f};
    if (p0) v0 = __builtin_nontemporal_load(&vocab[q0]);
    if (p1) v1 = __builtin_nontemporal_load(&vocab[q1]);

    vfloat4* tv = (vfloat4*)tile;
    const vfloat4 z = {0.f, 0.f, 0.f, 0.f};
    tv[tid]       = z;
    tv[tid + 256] = z;
    __syncthreads();

    // scatter sparse entries landing in [e0, e0+EPB) directly into the tile
    for (int r = bt0; r <= btL; ++r) {
        const int base = r * V - e0;
        const int bb   = r >> 7;
        const int n    = cnt[bb];
        const int*   ub = u  + bb * S_ENC;
        const float* vb = vs + r  * S_ENC;
        for (int i = tid; i < n; i += 256) {
            const int d = base + ub[i];
            if ((unsigned)d < (unsigned)EPB) tile[d] = vb[i];
        }
    }
    __syncthreads();

    // baseline mix + tile add + NT store
    if (p0) {
        const int e = q0 << 2;
        vfloat4 o;
        const int a = e / V, b2 = (e + 3) / V;
        if (a == b2) {
            const float4 P = params[a];
            o = v0 * P.x - P.y;
        } else {
            #pragma unroll
            for (int j = 0; j < 4; ++j) {
                const float4 P = params[(e + j) / V];
                o[j] = v0[j] * P.x - P.y;
            }
        }
        o += tv[tid];
        __builtin_nontemporal_store(o, &out[q0]);
    }
    if (p1) {
        const int e = q1 << 2;
        vfloat4 o;
        const int a = e / V, b2 = (e + 3) / V;
        if (a == b2) {
            const float4 P = params[a];
            o = v1 * P.x - P.y;
        } else {
            #pragma unroll
            for (int j = 0; j < 4; ++j) {
                const float4 P = params[(e + j) / V];
                o[j] = v1[j] * P.x - P.y;
            }
        }
        o += tv[tid + 256];
        __builtin_nontemporal_store(o, &out[q1]);
    }
}

extern "C" void kernel_launch(void* const* d_in, const int* in_sizes, int n_in,
                              void* d_out, int out_size, void* d_ws, size_t ws_size,
                              hipStream_t stream) {
    const int*   tokens  = (const int*)  d_in[0];
    const float* context = (const float*)d_in[1];
    const float* dec_in  = (const float*)d_in[2];
    const float* dec_out = (const float*)d_in[3];
    const float* vocab   = (const float*)d_in[4];
    const float* attn    = (const float*)d_in[5];
    // d_in[6] = encoder_outputs (unused by reference)
    const float* Wc = (const float*)d_in[7];
    const float* bc = (const float*)d_in[8];
    const float* Wo = (const float*)d_in[9];
    const float* bo = (const float*)d_in[10];
    const float* Wi = (const float*)d_in[11];
    const float* bi = (const float*)d_in[12];

    float* out = (float*)d_out;
    char*  ws  = (char*)d_ws;
    float4* params = (float4*)ws;                        // 16384 B
    int*    u      = (int*)  (ws + 16384);               // 12800 B
    int*    rnk    = (int*)  (ws + 29184);               // 12800 B
    int*    cnt    = (int*)  (ws + 41984);               // 32 B
    float*  vs     = (float*)(ws + 42048);               // 1638400 B

    build_kernel<<<B, 256, 0, stream>>>(tokens, u, rnk, cnt);

    prep_kernel<<<B * T, 256, 0, stream>>>(context, dec_in, dec_out, attn,
                                           Wc, bc, Wo, bo, Wi, bi,
                                           rnk, cnt, params, vs);

    const int nb = (TOTAL4 + QPB - 1) / QPB;             // 25,129 blocks
    mix_kernel<<<nb, 256, 0, stream>>>(
        (const vfloat4*)vocab, (const float4*)params, u, cnt, vs, (vfloat4*)out);
}

// Round 3
// 366.754 us; speedup vs baseline: 1.1119x; 1.0078x over previous
//
#include <hip/hip_runtime.h>
#include <math.h>

#define B 8
#define T 128
#define S_ENC 400
#define H 256
#define V 50257
#define HASH_SZ 1024        // power of 2, load factor 400/1024
#define NTOT (B * T * V)    // 51,463,168 elements (divisible by 4)
#define TOTAL4 (NTOT / 4)   // 12,865,792 float4
#define EPB 4096            // elements per mix block (16 KB LDS tile)
#define QPB (EPB / 4)       // float4 per mix block

typedef float vfloat4 __attribute__((ext_vector_type(4)));  // nontemporal-compatible

// ---------------------------------------------------------------------------
// Workspace layout (total ~1.68 MB):
//   params : float4[B*T]              @ 0                (16384 B)
//   u      : int[B][S_ENC]            @ 16384            (12800 B)  unique tokens
//   rnk    : int[B][S_ENC]            @ 29184            (12800 B)  s -> rank in u
//   cnt    : int[B]                   @ 41984            (32 B)
//   vs     : float[B*T][S_ENC]        @ 42048            (1638400 B) (1-p)*merged_attn
// ---------------------------------------------------------------------------

// Kernel A: one block per batch b (8 blocks). Dedup tokens via LDS hash,
// emit unique token list u[b], rank map rnk[b][s], count cnt[b].
// Rank assignment must be single-block-deterministic so that u (written here)
// and vs (written by prep via rnk) stay consistently paired.
__global__ __launch_bounds__(256) void build_kernel(
    const int* __restrict__ tokens,
    int* __restrict__ u, int* __restrict__ rnk, int* __restrict__ cnt)
{
    __shared__ int hk[HASH_SZ];
    __shared__ int hr[HASH_SZ];
    __shared__ int c;
    const int b = blockIdx.x, tid = threadIdx.x;

    for (int i = tid; i < HASH_SZ; i += 256) hk[i] = -1;
    if (tid == 0) c = 0;
    __syncthreads();

    for (int s = tid; s < S_ENC; s += 256) {
        const int tk = tokens[b * S_ENC + s];
        unsigned h = ((unsigned)tk * 2654435761u >> 16) & (HASH_SZ - 1);
        for (;;) {
            int prev = atomicCAS(&hk[h], -1, tk);
            if (prev == -1 || prev == tk) break;
            h = (h + 1) & (HASH_SZ - 1);
        }
    }
    __syncthreads();

    for (int i = tid; i < HASH_SZ; i += 256) {
        if (hk[i] != -1) {
            const int r = atomicAdd(&c, 1);
            hr[i] = r;
            u[b * S_ENC + r] = hk[i];
        }
    }
    __syncthreads();

    for (int s = tid; s < S_ENC; s += 256) {
        const int tk = tokens[b * S_ENC + s];
        unsigned h = ((unsigned)tk * 2654435761u >> 16) & (HASH_SZ - 1);
        while (hk[h] != tk) h = (h + 1) & (HASH_SZ - 1);
        rnk[b * S_ENC + s] = hr[h];
    }
    if (tid == 0) cnt[b] = c;
}

// ---------------------------------------------------------------------------
// Kernel B: one block per (b,t). p_gen + merged sparse values (dense 400-slot
// array via precomputed rank map), logsumexp, writes
// params[bt] = (p, (1-p)*lse, (1-p), 0) and vs[bt][r] = (1-p)*val[r].
// ---------------------------------------------------------------------------
__global__ __launch_bounds__(256) void prep_kernel(
    const float* __restrict__ context,
    const float* __restrict__ dec_in,
    const float* __restrict__ dec_out,
    const float* __restrict__ attn,
    const float* __restrict__ Wc, const float* __restrict__ bc,
    const float* __restrict__ Wo, const float* __restrict__ bo,
    const float* __restrict__ Wi, const float* __restrict__ bi,
    const int* __restrict__ rnk, const int* __restrict__ cnt,
    float4* __restrict__ params, float* __restrict__ vs)
{
    __shared__ float val[S_ENC];
    __shared__ float s_pg[4], s_m[4], s_se[4];
    __shared__ float s_mb, s_q;
    const int bt   = blockIdx.x;
    const int b    = bt >> 7;            // T = 128
    const int tid  = threadIdx.x;
    const int lane = tid & 63;
    const int wave = tid >> 6;

    for (int i = tid; i < S_ENC; i += 256) val[i] = 0.0f;

    // p_gen partial: H == 256 == blockDim, one element per thread
    {
        float v = context[bt * H + tid] * Wc[tid]
                + dec_out[bt * H + tid] * Wo[tid]
                + dec_in [bt * H + tid] * Wi[tid];
        #pragma unroll
        for (int off = 32; off; off >>= 1) v += __shfl_down(v, off, 64);
        if (lane == 0) s_pg[wave] = v;
    }
    __syncthreads();

    for (int s = tid; s < S_ENC; s += 256)
        atomicAdd(&val[rnk[b * S_ENC + s]], attn[bt * S_ENC + s]);
    __syncthreads();

    const int n = cnt[b];
    {
        float m = 0.0f;   // zero entries exist (V >> n) so max >= 0
        for (int i = tid; i < n; i += 256) m = fmaxf(m, val[i]);
        #pragma unroll
        for (int off = 32; off; off >>= 1) m = fmaxf(m, __shfl_down(m, off, 64));
        if (lane == 0) s_m[wave] = m;
    }
    __syncthreads();
    if (tid == 0) s_mb = fmaxf(fmaxf(s_m[0], s_m[1]), fmaxf(s_m[2], s_m[3]));
    __syncthreads();
    {
        const float m = s_mb;
        float se = 0.0f;
        for (int i = tid; i < n; i += 256) se += expf(val[i] - m);
        #pragma unroll
        for (int off = 32; off; off >>= 1) se += __shfl_down(se, off, 64);
        if (lane == 0) s_se[wave] = se;
    }
    __syncthreads();
    if (tid == 0) {
        const float m   = s_mb;
        float se  = s_se[0] + s_se[1] + s_se[2] + s_se[3]
                  + (float)(V - n) * expf(-m);
        float lse = m + logf(se);
        float x   = s_pg[0] + s_pg[1] + s_pg[2] + s_pg[3]
                  + bc[0] + bo[0] + bi[0];
        float p   = 1.0f / (1.0f + expf(-x));
        float q   = 1.0f - p;
        params[bt] = make_float4(p, q * lse, q, 0.0f);
        s_q = q;
    }
    __syncthreads();
    const float q = s_q;
    for (int i = tid; i < n; i += 256) vs[bt * S_ENC + i] = q * val[i];
}

// ---------------------------------------------------------------------------
// Kernel C: fused streaming mix + sparse copy via direct-scatter LDS tile.
// Each block owns 4096 contiguous elements (4 float4/thread, 16 KB LDS).
// Sparse entries landing in-range scatter straight into the tile — provably
// collision-free (tokens unique per row; two rows in a block can't alias:
// d1==d2 would need tok1 == tok2 + V, impossible) — plain stores, no atomics.
// Row-uniform fast path: blocks fully inside one row (92%) use one scalar P,
// zero per-thread divisions. NT loads issued before zero/scan to hide HBM
// latency. 16 KB LDS: occupancy stays thread-limited at 8 blocks/CU.
// ---------------------------------------------------------------------------
__global__ __launch_bounds__(256) void mix_kernel(
    const vfloat4* __restrict__ vocab,
    const float4*  __restrict__ params,
    const int*     __restrict__ u,
    const int*     __restrict__ cnt,
    const float*   __restrict__ vs,
    vfloat4* __restrict__ out)
{
    __shared__ float tile[EPB];
    const int tid = threadIdx.x;
    const int qb  = blockIdx.x * QPB;
    const int e0  = blockIdx.x * EPB;
    const int eL  = min(e0 + EPB - 1, NTOT - 1);
    const int bt0 = e0 / V;                        // magic-mul (V constexpr)
    const int btL = eL / V;

    int  q[4];
    bool p[4];
    vfloat4 v[4];
    #pragma unroll
    for (int j = 0; j < 4; ++j) {
        q[j] = qb + tid + 256 * j;
        p[j] = q[j] < TOTAL4;
        if (p[j]) v[j] = __builtin_nontemporal_load(&vocab[q[j]]);
    }

    vfloat4* tv = (vfloat4*)tile;
    const vfloat4 z = {0.f, 0.f, 0.f, 0.f};
    #pragma unroll
    for (int j = 0; j < 4; ++j) tv[tid + 256 * j] = z;
    __syncthreads();

    // scatter sparse entries landing in [e0, e0+EPB) directly into the tile
    for (int r = bt0; r <= btL; ++r) {
        const int base = r * V - e0;
        const int bb   = r >> 7;
        const int n    = cnt[bb];
        const int*   ub = u  + bb * S_ENC;
        const float* vb = vs + r  * S_ENC;
        for (int i = tid; i < n; i += 256) {
            const int d = base + ub[i];
            if ((unsigned)d < (unsigned)EPB) tile[d] = vb[i];
        }
    }
    __syncthreads();

    if (bt0 == btL) {
        // row-uniform fast path: one scalar P for the whole block
        const float4 P = params[bt0];
        #pragma unroll
        for (int j = 0; j < 4; ++j) {
            if (p[j]) {
                vfloat4 o = v[j] * P.x - P.y;
                o += tv[tid + 256 * j];
                __builtin_nontemporal_store(o, &out[q[j]]);
            }
        }
    } else {
        #pragma unroll
        for (int j = 0; j < 4; ++j) {
            if (p[j]) {
                const int e = q[j] << 2;
                vfloat4 o;
                const int a = e / V, b2 = (e + 3) / V;
                if (a == b2) {
                    const float4 P = params[a];
                    o = v[j] * P.x - P.y;
                } else {
                    #pragma unroll
                    for (int k = 0; k < 4; ++k) {
                        const float4 P = params[(e + k) / V];
                        o[k] = v[j][k] * P.x - P.y;
                    }
                }
                o += tv[tid + 256 * j];
                __builtin_nontemporal_store(o, &out[q[j]]);
            }
        }
    }
}

extern "C" void kernel_launch(void* const* d_in, const int* in_sizes, int n_in,
                              void* d_out, int out_size, void* d_ws, size_t ws_size,
                              hipStream_t stream) {
    const int*   tokens  = (const int*)  d_in[0];
    const float* context = (const float*)d_in[1];
    const float* dec_in  = (const float*)d_in[2];
    const float* dec_out = (const float*)d_in[3];
    const float* vocab   = (const float*)d_in[4];
    const float* attn    = (const float*)d_in[5];
    // d_in[6] = encoder_outputs (unused by reference)
    const float* Wc = (const float*)d_in[7];
    const float* bc = (const float*)d_in[8];
    const float* Wo = (const float*)d_in[9];
    const float* bo = (const float*)d_in[10];
    const float* Wi = (const float*)d_in[11];
    const float* bi = (const float*)d_in[12];

    float* out = (float*)d_out;
    char*  ws  = (char*)d_ws;
    float4* params = (float4*)ws;                        // 16384 B
    int*    u      = (int*)  (ws + 16384);               // 12800 B
    int*    rnk    = (int*)  (ws + 29184);               // 12800 B
    int*    cnt    = (int*)  (ws + 41984);               // 32 B
    float*  vs     = (float*)(ws + 42048);               // 1638400 B

    build_kernel<<<B, 256, 0, stream>>>(tokens, u, rnk, cnt);

    prep_kernel<<<B * T, 256, 0, stream>>>(context, dec_in, dec_out, attn,
                                           Wc, bc, Wo, bo, Wi, bi,
                                           rnk, cnt, params, vs);

    const int nb = (TOTAL4 + QPB - 1) / QPB;             // 12,565 blocks
    mix_kernel<<<nb, 256, 0, stream>>>(
        (const vfloat4*)vocab, (const float4*)params, u, cnt, vs, (vfloat4*)out);
}